// Round 1
// baseline (746.861 us; speedup 1.0000x reference)
//
#include <hip/hip_runtime.h>
#include <hip/hip_bf16.h>
#include <math.h>

#define N_NODES 100000
#define N_EDGES 1600000
#define NODE_F  64
#define EDGE_F  16
#define SF_DIM  80   // EDGE_F + NODE_F
#define OUT_F   64

// ---------------------------------------------------------------------------
// Kernel 1: edge scatter. One thread per (edge, feature) pair, feature-major
// so a wave's lanes cover contiguous features of (at most two) edges:
//   - coalesced reads of edge_feats rows (f < 16) and feat[src] rows (f >= 16)
//   - atomicAdd into sum_f[dst*80 + f] (contiguous within an edge's row)
//   - lane f==0 also bumps the degree histogram
// 128M fire-and-forget f32 atomics — expected bottleneck; baseline only.
// ---------------------------------------------------------------------------
__global__ __launch_bounds__(256) void edge_scatter(
    const float* __restrict__ feat,
    const float* __restrict__ edge_feats,
    const int*   __restrict__ src,
    const int*   __restrict__ dst,
    float*       __restrict__ sum_f,   // [N_NODES][80], pre-zeroed
    float*       __restrict__ deg)     // [N_NODES], pre-zeroed
{
    unsigned t = blockIdx.x * 256u + threadIdx.x;
    unsigned e = t / 80u;
    unsigned f = t - e * 80u;
    if (e >= N_EDGES) return;

    int d = dst[e];
    float v;
    if (f < 16u) {
        v = edge_feats[e * 16u + f];
        if (f == 0u) atomicAdd(&deg[d], 1.0f);
    } else {
        int s = src[e];
        v = feat[(unsigned)s * 64u + (f - 16u)];
    }
    atomicAdd(&sum_f[(unsigned)d * 80u + f], v);
}

// ---------------------------------------------------------------------------
// Kernel 2: per-node normalize + 80x64 GEMM + bias + SELU.
// Block = 256 (4 waves). W (80x64 f32 = 20 KB) staged in LDS once per block.
// One wave per node, lane = output feature j:
//   out[n][j] = selu( (sum_k sf[k]*nrm * W[k][j]) * nrm + bias[j] )
// sf row staged per-wave in LDS for broadcast reads (same-address = free);
// W[k*64+lane] is a 2-way bank alias (free on gfx950, G4/m136).
// ---------------------------------------------------------------------------
__global__ __launch_bounds__(256) void node_gemm(
    const float* __restrict__ sum_f,
    const float* __restrict__ deg,
    const float* __restrict__ weight,  // [80][64]
    const float* __restrict__ bias,    // [64]
    float*       __restrict__ out)     // [N_NODES][64]
{
    __shared__ float Wl[SF_DIM * OUT_F];
    __shared__ float sf[4][SF_DIM];

    int tid = threadIdx.x;
    for (int i = tid; i < SF_DIM * OUT_F; i += 256) Wl[i] = weight[i];
    __syncthreads();

    int wv = tid >> 6;
    int ln = tid & 63;
    float b = bias[ln];

    const float SC = 1.0507009873554805f;   // selu scale
    const float AL = 1.6732632423543772f;   // selu alpha

    for (int n = blockIdx.x * 4 + wv; n < N_NODES; n += gridDim.x * 4) {
        float nrm = rsqrtf(fmaxf(deg[n], 1.0f));

        // stage normalized sum_f row into this wave's LDS slot
        float va = sum_f[n * SF_DIM + ln];
        sf[wv][ln] = va * nrm;
        if (ln < 16) {
            float vb = sum_f[n * SF_DIM + 64 + ln];
            sf[wv][64 + ln] = vb * nrm;
        }
        // same-wave LDS write->read: HW/compiler ordering via lgkmcnt, no barrier

        float acc = 0.f;
        #pragma unroll
        for (int k = 0; k < SF_DIM; ++k)
            acc = fmaf(sf[wv][k], Wl[k * OUT_F + ln], acc);

        float o = acc * nrm + b;
        out[n * OUT_F + ln] = (o > 0.f) ? SC * o : SC * AL * expm1f(o);
    }
}

extern "C" void kernel_launch(void* const* d_in, const int* in_sizes, int n_in,
                              void* d_out, int out_size, void* d_ws, size_t ws_size,
                              hipStream_t stream) {
    const float* feat       = (const float*)d_in[0];
    const float* edge_feats = (const float*)d_in[1];
    const int*   src        = (const int*)d_in[2];
    const int*   dst        = (const int*)d_in[3];
    const float* weight     = (const float*)d_in[4];
    const float* bias       = (const float*)d_in[5];
    float* out = (float*)d_out;

    float* sum_f = (float*)d_ws;                       // 100000*80 f32 = 32 MB
    float* deg   = sum_f + (size_t)N_NODES * SF_DIM;   // 100000 f32

    size_t zero_bytes = ((size_t)N_NODES * SF_DIM + N_NODES) * sizeof(float);
    hipMemsetAsync(d_ws, 0, zero_bytes, stream);

    // 1.6M edges * 80 features = 128M threads, exactly 500000 blocks of 256
    edge_scatter<<<dim3(500000), dim3(256), 0, stream>>>(
        feat, edge_feats, src, dst, sum_f, deg);

    node_gemm<<<dim3(2048), dim3(256), 0, stream>>>(
        sum_f, deg, weight, bias, out);
}